// Round 2
// baseline (196.030 us; speedup 1.0000x reference)
//
#include <hip/hip_runtime.h>
#include <hip/hip_bf16.h>
#include <stdint.h>

#define GAMMA 0.002f
#define MDIM 4096
#define NDIM 8192
#define KDIM 512
#define BM 128
#define BN 128
#define BK 32

typedef short v8s  __attribute__((ext_vector_type(8)));
typedef float v16f __attribute__((ext_vector_type(16)));

__device__ __forceinline__ unsigned short f32_to_bf16_rne(float f) {
    union { float f; uint32_t u; } v; v.f = f;
    uint32_t u = v.u;
    return (unsigned short)((u + 0x7fffu + ((u >> 16) & 1u)) >> 16);
}

__device__ __forceinline__ void gl_lds16(const void* g, void* l) {
    __builtin_amdgcn_global_load_lds(
        (const __attribute__((address_space(1))) uint32_t*)g,
        (__attribute__((address_space(3))) uint32_t*)l, 16, 0, 0);
}

// One block per row (x rows then sv rows): convert 512 fp32 -> bf16 (RNE)
// and emit -gamma*sum(v^2) in fp32.
__global__ __launch_bounds__(256) void convert_all(
    const float* __restrict__ x, const float* __restrict__ sv,
    unsigned short* __restrict__ xb, unsigned short* __restrict__ svb,
    float* __restrict__ arow, float* __restrict__ ccol) {
    int row = blockIdx.x;
    const float* src;
    unsigned short* dst;
    float* red_out;
    if (row < MDIM) {
        src = x + (size_t)row * KDIM;
        dst = xb + (size_t)row * KDIM;
        red_out = arow + row;
    } else {
        int r = row - MDIM;
        src = sv + (size_t)r * KDIM;
        dst = svb + (size_t)r * KDIM;
        red_out = ccol + r;
    }
    int t = threadIdx.x;
    float2 f = ((const float2*)src)[t];
    ushort2 b;
    b.x = f32_to_bf16_rne(f.x);
    b.y = f32_to_bf16_rne(f.y);
    ((ushort2*)dst)[t] = b;
    float s = f.x * f.x + f.y * f.y;
    #pragma unroll
    for (int off = 32; off > 0; off >>= 1) s += __shfl_down(s, off, 64);
    __shared__ float red[4];
    if ((t & 63) == 0) red[t >> 6] = s;
    __syncthreads();
    if (t == 0) *red_out = -GAMMA * (red[0] + red[1] + red[2] + red[3]);
}

// out[m,n] = exp(arow[m] + ccol[n] + 2*gamma*dot(x[m], sv[n]))
// 128x128 tile, 4 waves each owning 64x64 as 2x2 tiles of 32x32x16 MFMA.
__global__ __launch_bounds__(256) void rbf_gemm(
    const unsigned short* __restrict__ A,   // [4096,512] bf16
    const unsigned short* __restrict__ B,   // [8192,512] bf16
    const float* __restrict__ arow,         // [4096]  = -g*||x||^2
    const float* __restrict__ ccol,         // [8192]  = -g*||sv||^2
    float* __restrict__ out) {

    __shared__ __align__(16) unsigned short sA[BM * BK];  // 8 KiB
    __shared__ __align__(16) unsigned short sB[BN * BK];  // 8 KiB

    const int tid  = threadIdx.x;
    const int lane = tid & 63;
    const int wave = tid >> 6;          // 0..3
    const int wm   = wave >> 1;         // 0..1
    const int wn   = wave & 1;          // 0..1
    const int row0 = blockIdx.y * BM;
    const int col0 = blockIdx.x * BN;

    // staging: thread covers row (tid>>2) (+64 for 2nd issue), 8 elems at col (tid&3)*8
    const unsigned short* aptr = A + (size_t)(row0 + (tid >> 2)) * KDIM + (tid & 3) * 8;
    const unsigned short* bptr = B + (size_t)(col0 + (tid >> 2)) * KDIM + (tid & 3) * 8;
    unsigned short* sAp = &sA[tid * 8];
    unsigned short* sBp = &sB[tid * 8];

    v16f acc[2][2];
    #pragma unroll
    for (int i = 0; i < 2; i++)
        #pragma unroll
        for (int j = 0; j < 2; j++) acc[i][j] = (v16f)0.0f;

    const int r32 = lane & 31;   // row (A) / col (B) within a 32-tile
    const int kh  = lane >> 5;   // 0..1 -> k-half offset kh*8

    for (int k0 = 0; k0 < KDIM; k0 += BK) {
        gl_lds16(aptr + k0, sAp);
        gl_lds16(aptr + (size_t)64 * KDIM + k0, sAp + 2048);
        gl_lds16(bptr + k0, sBp);
        gl_lds16(bptr + (size_t)64 * KDIM + k0, sBp + 2048);
        __syncthreads();

        v8s af[2][2], bf[2][2];   // [tile][kstep]
        #pragma unroll
        for (int ks = 0; ks < 2; ks++) {
            #pragma unroll
            for (int i = 0; i < 2; i++) {
                af[i][ks] = *(const v8s*)&sA[(wm * 64 + i * 32 + r32) * BK + ks * 16 + kh * 8];
                bf[i][ks] = *(const v8s*)&sB[(wn * 64 + i * 32 + r32) * BK + ks * 16 + kh * 8];
            }
        }
        #pragma unroll
        for (int ks = 0; ks < 2; ks++)
            #pragma unroll
            for (int i = 0; i < 2; i++)
                #pragma unroll
                for (int j = 0; j < 2; j++)
                    acc[i][j] = __builtin_amdgcn_mfma_f32_32x32x16_bf16(
                        af[i][ks], bf[j][ks], acc[i][j], 0, 0, 0);
        __syncthreads();
    }

    // stage per-block row/col bias terms into (now free) LDS
    float* fA = (float*)sA;   // 128 floats
    float* fC = (float*)sB;   // 128 floats
    if (tid < 128) fA[tid] = arow[row0 + tid];
    else           fC[tid - 128] = ccol[col0 + tid - 128];
    __syncthreads();

    const float tg = 2.0f * GAMMA;
    #pragma unroll
    for (int i = 0; i < 2; i++) {
        #pragma unroll
        for (int j = 0; j < 2; j++) {
            const int cl = wn * 64 + j * 32 + r32;
            const float cc = fC[cl];
            #pragma unroll
            for (int reg = 0; reg < 16; reg++) {
                const int rr = wm * 64 + i * 32 + (reg & 3) + 8 * (reg >> 2) + 4 * kh;
                out[(size_t)(row0 + rr) * NDIM + (col0 + cl)] =
                    __expf(fmaf(tg, acc[i][j][reg], fA[rr] + cc));
            }
        }
    }
}

extern "C" void kernel_launch(void* const* d_in, const int* in_sizes, int n_in,
                              void* d_out, int out_size, void* d_ws, size_t ws_size,
                              hipStream_t stream) {
    const float* x  = (const float*)d_in[0];   // [4096,512]
    const float* sv = (const float*)d_in[1];   // [8192,512]
    float* out = (float*)d_out;

    // ws layout: xb (4 MiB) | svb (8 MiB) | arow (16 KiB) | ccol (32 KiB)
    unsigned short* xb  = (unsigned short*)d_ws;
    unsigned short* svb = xb + (size_t)MDIM * KDIM;
    float* arow = (float*)(svb + (size_t)NDIM * KDIM);
    float* ccol = arow + MDIM;

    hipLaunchKernelGGL(convert_all, dim3(MDIM + NDIM), dim3(256), 0, stream,
                       x, sv, xb, svb, arow, ccol);
    hipLaunchKernelGGL(rbf_gemm, dim3(NDIM / BN, MDIM / BM), dim3(256), 0, stream,
                       xb, svb, arow, ccol, out);
}

// Round 3
// 194.399 us; speedup vs baseline: 1.0084x; 1.0084x over previous
//
#include <hip/hip_runtime.h>
#include <hip/hip_bf16.h>
#include <stdint.h>

#define GAMMA 0.002f
#define MDIM 4096
#define NDIM 8192
#define KDIM 512
#define BM 128
#define BN 128
#define BK 32

typedef short v8s  __attribute__((ext_vector_type(8)));
typedef float v16f __attribute__((ext_vector_type(16)));

__device__ __forceinline__ unsigned short f32_to_bf16_rne(float f) {
    union { float f; uint32_t u; } v; v.f = f;
    uint32_t u = v.u;
    return (unsigned short)((u + 0x7fffu + ((u >> 16) & 1u)) >> 16);
}

__device__ __forceinline__ void gl_lds16(const void* g, void* l) {
    __builtin_amdgcn_global_load_lds(
        (const __attribute__((address_space(1))) uint32_t*)g,
        (__attribute__((address_space(3))) uint32_t*)l, 16, 0, 0);
}

// One block per row (x rows then sv rows): convert 512 fp32 -> bf16 (RNE)
// and emit -gamma*sum(v^2) in fp32.
__global__ __launch_bounds__(256) void convert_all(
    const float* __restrict__ x, const float* __restrict__ sv,
    unsigned short* __restrict__ xb, unsigned short* __restrict__ svb,
    float* __restrict__ arow, float* __restrict__ ccol) {
    int row = blockIdx.x;
    const float* src;
    unsigned short* dst;
    float* red_out;
    if (row < MDIM) {
        src = x + (size_t)row * KDIM;
        dst = xb + (size_t)row * KDIM;
        red_out = arow + row;
    } else {
        int r = row - MDIM;
        src = sv + (size_t)r * KDIM;
        dst = svb + (size_t)r * KDIM;
        red_out = ccol + r;
    }
    int t = threadIdx.x;
    float2 f = ((const float2*)src)[t];
    ushort2 b;
    b.x = f32_to_bf16_rne(f.x);
    b.y = f32_to_bf16_rne(f.y);
    ((ushort2*)dst)[t] = b;
    float s = f.x * f.x + f.y * f.y;
    #pragma unroll
    for (int off = 32; off > 0; off >>= 1) s += __shfl_down(s, off, 64);
    __shared__ float red[4];
    if ((t & 63) == 0) red[t >> 6] = s;
    __syncthreads();
    if (t == 0) *red_out = -GAMMA * (red[0] + red[1] + red[2] + red[3]);
}

// out[m,n] = exp(arow[m] + ccol[n] + 2*gamma*dot(x[m], sv[n]))
// 128x128 tile, 4 waves each owning 64x64 as 2x2 tiles of 32x32x16 MFMA.
// LDS layout XOR-swizzled: k-granule c (16B) of row r lives at granule c^(r&3),
// implemented by permuting the GLOBAL source chunk per staging lane (LDS writes
// stay lane-contiguous as global_load_lds requires). Makes ds_read_b128 of the
// 32x32 fragment pattern hit all 32 banks evenly (8/bank = wave64 floor).
__global__ __launch_bounds__(256) void rbf_gemm(
    const unsigned short* __restrict__ A,   // [4096,512] bf16
    const unsigned short* __restrict__ B,   // [8192,512] bf16
    const float* __restrict__ arow,         // [4096]  = -g*||x||^2
    const float* __restrict__ ccol,         // [8192]  = -g*||sv||^2
    float* __restrict__ out) {

    __shared__ __align__(16) unsigned short sA[BM * BK];  // 8 KiB
    __shared__ __align__(16) unsigned short sB[BN * BK];  // 8 KiB

    const int tid  = threadIdx.x;
    const int lane = tid & 63;
    const int wave = tid >> 6;          // 0..3
    const int wm   = wave >> 1;         // 0..1
    const int wn   = wave & 1;          // 0..1
    const int row0 = blockIdx.y * BM;
    const int col0 = blockIdx.x * BN;

    // staging: thread covers row (tid>>2) (+64 for 2nd issue). LDS granule tid
    // holds swizzled chunk (tid&3), so fetch global chunk (tid&3)^(row&3).
    // (row+64)&3 == row&3, so the same pointer works for the second issue.
    const int srow = tid >> 2;
    const int sch  = (tid & 3) ^ (srow & 3);
    const unsigned short* aptr = A + (size_t)(row0 + srow) * KDIM + sch * 8;
    const unsigned short* bptr = B + (size_t)(col0 + srow) * KDIM + sch * 8;
    unsigned short* sAp = &sA[tid * 8];
    unsigned short* sBp = &sB[tid * 8];

    v16f acc[2][2];
    #pragma unroll
    for (int i = 0; i < 2; i++)
        #pragma unroll
        for (int j = 0; j < 2; j++) acc[i][j] = (v16f)0.0f;

    const int r32 = lane & 31;   // row (A) / col (B) within a 32-tile
    const int kh  = lane >> 5;   // 0..1 -> k-half offset kh*8
    const int sw  = r32 & 3;     // read-side swizzle key

    for (int k0 = 0; k0 < KDIM; k0 += BK) {
        gl_lds16(aptr + k0, sAp);
        gl_lds16(aptr + (size_t)64 * KDIM + k0, sAp + 2048);
        gl_lds16(bptr + k0, sBp);
        gl_lds16(bptr + (size_t)64 * KDIM + k0, sBp + 2048);
        __syncthreads();

        v8s af[2][2], bf[2][2];   // [tile][kstep]
        #pragma unroll
        for (int ks = 0; ks < 2; ks++) {
            const int ch = ((ks * 2 + kh) ^ sw) * 8;  // swizzled chunk offset (elems)
            #pragma unroll
            for (int i = 0; i < 2; i++) {
                af[i][ks] = *(const v8s*)&sA[(wm * 64 + i * 32 + r32) * BK + ch];
                bf[i][ks] = *(const v8s*)&sB[(wn * 64 + i * 32 + r32) * BK + ch];
            }
        }
        #pragma unroll
        for (int ks = 0; ks < 2; ks++)
            #pragma unroll
            for (int i = 0; i < 2; i++)
                #pragma unroll
                for (int j = 0; j < 2; j++)
                    acc[i][j] = __builtin_amdgcn_mfma_f32_32x32x16_bf16(
                        af[i][ks], bf[j][ks], acc[i][j], 0, 0, 0);
        __syncthreads();
    }

    // stage per-block row/col bias terms into (now free) LDS
    float* fA = (float*)sA;   // 128 floats
    float* fC = (float*)sB;   // 128 floats
    if (tid < 128) fA[tid] = arow[row0 + tid];
    else           fC[tid - 128] = ccol[col0 + tid - 128];
    __syncthreads();

    const float tg = 2.0f * GAMMA;
    #pragma unroll
    for (int i = 0; i < 2; i++) {
        #pragma unroll
        for (int j = 0; j < 2; j++) {
            const int cl = wn * 64 + j * 32 + r32;
            const float cc = fC[cl];
            #pragma unroll
            for (int reg = 0; reg < 16; reg++) {
                const int rr = wm * 64 + i * 32 + (reg & 3) + 8 * (reg >> 2) + 4 * kh;
                out[(size_t)(row0 + rr) * NDIM + (col0 + cl)] =
                    __expf(fmaf(tg, acc[i][j][reg], fA[rr] + cc));
            }
        }
    }
}

extern "C" void kernel_launch(void* const* d_in, const int* in_sizes, int n_in,
                              void* d_out, int out_size, void* d_ws, size_t ws_size,
                              hipStream_t stream) {
    const float* x  = (const float*)d_in[0];   // [4096,512]
    const float* sv = (const float*)d_in[1];   // [8192,512]
    float* out = (float*)d_out;

    // ws layout: xb (4 MiB) | svb (8 MiB) | arow (16 KiB) | ccol (32 KiB)
    unsigned short* xb  = (unsigned short*)d_ws;
    unsigned short* svb = xb + (size_t)MDIM * KDIM;
    float* arow = (float*)(svb + (size_t)NDIM * KDIM);
    float* ccol = arow + MDIM;

    hipLaunchKernelGGL(convert_all, dim3(MDIM + NDIM), dim3(256), 0, stream,
                       x, sv, xb, svb, arow, ccol);
    hipLaunchKernelGGL(rbf_gemm, dim3(NDIM / BN, MDIM / BM), dim3(256), 0, stream,
                       xb, svb, arow, ccol, out);
}

// Round 4
// 189.310 us; speedup vs baseline: 1.0355x; 1.0269x over previous
//
#include <hip/hip_runtime.h>
#include <hip/hip_bf16.h>
#include <stdint.h>

#define GAMMA 0.002f
#define MDIM 4096
#define NDIM 8192
#define KDIM 512
#define BM 128
#define BN 128
#define BK 32
#define KITERS (KDIM / BK)   // 16

typedef short v8s  __attribute__((ext_vector_type(8)));
typedef float v16f __attribute__((ext_vector_type(16)));

__device__ __forceinline__ unsigned short f32_to_bf16_rne(float f) {
    union { float f; uint32_t u; } v; v.f = f;
    uint32_t u = v.u;
    return (unsigned short)((u + 0x7fffu + ((u >> 16) & 1u)) >> 16);
}

__device__ __forceinline__ void gl_lds16(const void* g, void* l) {
    __builtin_amdgcn_global_load_lds(
        (const __attribute__((address_space(1))) uint32_t*)g,
        (__attribute__((address_space(3))) uint32_t*)l, 16, 0, 0);
}

// One block per row (x rows then sv rows): convert 512 fp32 -> bf16 (RNE)
// and emit -gamma*sum(v^2) in fp32.
__global__ __launch_bounds__(256) void convert_all(
    const float* __restrict__ x, const float* __restrict__ sv,
    unsigned short* __restrict__ xb, unsigned short* __restrict__ svb,
    float* __restrict__ arow, float* __restrict__ ccol) {
    int row = blockIdx.x;
    const float* src;
    unsigned short* dst;
    float* red_out;
    if (row < MDIM) {
        src = x + (size_t)row * KDIM;
        dst = xb + (size_t)row * KDIM;
        red_out = arow + row;
    } else {
        int r = row - MDIM;
        src = sv + (size_t)r * KDIM;
        dst = svb + (size_t)r * KDIM;
        red_out = ccol + r;
    }
    int t = threadIdx.x;
    float2 f = ((const float2*)src)[t];
    ushort2 b;
    b.x = f32_to_bf16_rne(f.x);
    b.y = f32_to_bf16_rne(f.y);
    ((ushort2*)dst)[t] = b;
    float s = f.x * f.x + f.y * f.y;
    #pragma unroll
    for (int off = 32; off > 0; off >>= 1) s += __shfl_down(s, off, 64);
    __shared__ float red[4];
    if ((t & 63) == 0) red[t >> 6] = s;
    __syncthreads();
    if (t == 0) *red_out = -GAMMA * (red[0] + red[1] + red[2] + red[3]);
}

// out[m,n] = exp(arow[m] + ccol[n] + 2*gamma*dot(x[m], sv[n]))
// 128x128 tile, 4 waves each owning 64x64 as 2x2 tiles of 32x32x16 MFMA.
// DOUBLE-BUFFERED LDS, one barrier per K-iter: the vmcnt(0) drain at each
// barrier waits on loads that had a full compute phase in flight.
// XOR chunk swizzle (granule c of row r at c^(r&3), applied on the GLOBAL
// source side since global_load_lds needs lane-contiguous LDS dests) keeps
// the 32x32 fragment ds_read_b128 pattern at the 8-access/bank floor.
__global__ __launch_bounds__(256) void rbf_gemm(
    const unsigned short* __restrict__ A,   // [4096,512] bf16
    const unsigned short* __restrict__ B,   // [8192,512] bf16
    const float* __restrict__ arow,         // [4096]  = -g*||x||^2
    const float* __restrict__ ccol,         // [8192]  = -g*||sv||^2
    float* __restrict__ out) {

    __shared__ __align__(16) unsigned short sA[2][BM * BK];  // 2 x 8 KiB
    __shared__ __align__(16) unsigned short sB[2][BN * BK];  // 2 x 8 KiB
    __shared__ float sBias[BM + BN];                          // 1 KiB

    const int tid  = threadIdx.x;
    const int lane = tid & 63;
    const int wave = tid >> 6;          // 0..3
    const int wm   = wave >> 1;         // 0..1
    const int wn   = wave & 1;          // 0..1
    const int row0 = blockIdx.y * BM;
    const int col0 = blockIdx.x * BN;

    // Bias staging up front; the main loop's barriers order it before epilogue.
    if (tid < BM) sBias[tid] = arow[row0 + tid];
    else          sBias[tid] = ccol[col0 + tid - BM];

    // staging: thread covers row (tid>>2) (+64 for 2nd issue). LDS granule tid
    // holds swizzled chunk (tid&3), so fetch global chunk (tid&3)^(row&3).
    // (row+64)&3 == row&3, so the same pointer works for the second issue.
    const int srow = tid >> 2;
    const int sch  = (tid & 3) ^ (srow & 3);
    const unsigned short* aptr = A + (size_t)(row0 + srow) * KDIM + sch * 8;
    const unsigned short* bptr = B + (size_t)(col0 + srow) * KDIM + sch * 8;

    v16f acc[2][2];
    #pragma unroll
    for (int i = 0; i < 2; i++)
        #pragma unroll
        for (int j = 0; j < 2; j++) acc[i][j] = (v16f)0.0f;

    const int r32 = lane & 31;   // row (A) / col (B) within a 32-tile
    const int kh  = lane >> 5;   // 0..1 -> k-half offset kh*8
    const int sw  = r32 & 3;     // read-side swizzle key

    // prologue: stage iter 0 into buffer 0
    gl_lds16(aptr, &sA[0][tid * 8]);
    gl_lds16(aptr + (size_t)64 * KDIM, &sA[0][tid * 8 + 2048]);
    gl_lds16(bptr, &sB[0][tid * 8]);
    gl_lds16(bptr + (size_t)64 * KDIM, &sB[0][tid * 8 + 2048]);

    #pragma unroll
    for (int k = 0; k < KITERS; ++k) {
        const int cur = k & 1;
        const int nxt = cur ^ 1;
        __syncthreads();   // drains vmcnt(0): buf[cur] ready; buf[nxt] reads done

        if (k + 1 < KITERS) {
            const int k0 = (k + 1) * BK;
            gl_lds16(aptr + k0, &sA[nxt][tid * 8]);
            gl_lds16(aptr + (size_t)64 * KDIM + k0, &sA[nxt][tid * 8 + 2048]);
            gl_lds16(bptr + k0, &sB[nxt][tid * 8]);
            gl_lds16(bptr + (size_t)64 * KDIM + k0, &sB[nxt][tid * 8 + 2048]);
        }

        v8s af[2][2], bf[2][2];   // [tile][kstep]
        #pragma unroll
        for (int ks = 0; ks < 2; ks++) {
            const int ch = ((ks * 2 + kh) ^ sw) * 8;  // swizzled chunk offset (elems)
            #pragma unroll
            for (int i = 0; i < 2; i++) {
                af[i][ks] = *(const v8s*)&sA[cur][(wm * 64 + i * 32 + r32) * BK + ch];
                bf[i][ks] = *(const v8s*)&sB[cur][(wn * 64 + i * 32 + r32) * BK + ch];
            }
        }
        #pragma unroll
        for (int ks = 0; ks < 2; ks++)
            #pragma unroll
            for (int i = 0; i < 2; i++)
                #pragma unroll
                for (int j = 0; j < 2; j++)
                    acc[i][j] = __builtin_amdgcn_mfma_f32_32x32x16_bf16(
                        af[i][ks], bf[j][ks], acc[i][j], 0, 0, 0);
        // no second barrier: next iter's barrier protects buf reuse
    }

    const float* fA = sBias;        // row biases
    const float* fC = sBias + BM;   // col biases
    const float tg = 2.0f * GAMMA;
    #pragma unroll
    for (int i = 0; i < 2; i++) {
        #pragma unroll
        for (int j = 0; j < 2; j++) {
            const int cl = wn * 64 + j * 32 + r32;
            const float cc = fC[cl];
            #pragma unroll
            for (int reg = 0; reg < 16; reg++) {
                const int rr = wm * 64 + i * 32 + (reg & 3) + 8 * (reg >> 2) + 4 * kh;
                out[(size_t)(row0 + rr) * NDIM + (col0 + cl)] =
                    __expf(fmaf(tg, acc[i][j][reg], fA[rr] + cc));
            }
        }
    }
}

extern "C" void kernel_launch(void* const* d_in, const int* in_sizes, int n_in,
                              void* d_out, int out_size, void* d_ws, size_t ws_size,
                              hipStream_t stream) {
    const float* x  = (const float*)d_in[0];   // [4096,512]
    const float* sv = (const float*)d_in[1];   // [8192,512]
    float* out = (float*)d_out;

    // ws layout: xb (4 MiB) | svb (8 MiB) | arow (16 KiB) | ccol (32 KiB)
    unsigned short* xb  = (unsigned short*)d_ws;
    unsigned short* svb = xb + (size_t)MDIM * KDIM;
    float* arow = (float*)(svb + (size_t)NDIM * KDIM);
    float* ccol = arow + MDIM;

    hipLaunchKernelGGL(convert_all, dim3(MDIM + NDIM), dim3(256), 0, stream,
                       x, sv, xb, svb, arow, ccol);
    hipLaunchKernelGGL(rbf_gemm, dim3(NDIM / BN, MDIM / BM), dim3(256), 0, stream,
                       xb, svb, arow, ccol, out);
}